// Round 1
// 125.980 us; speedup vs baseline: 1.0323x; 1.0323x over previous
//
#include <hip/hip_runtime.h>

#define HSZ 128
#define ISZ 28
#define TSZ 28
#define CSZ 10
#define BT  16     // batch rows per block
#define NT  512    // 8 waves, one 16-row hidden tile each
#define HP  136    // h row stride in halves
#define XP  32     // x row stride in halves (K padded 28->32)

typedef _Float16 half_t;
typedef _Float16 v8h __attribute__((ext_vector_type(8)));
typedef _Float16 v4h __attribute__((ext_vector_type(4)));
typedef float v4f __attribute__((ext_vector_type(4)));

__device__ __forceinline__ float fast_tanh(float x) {
    // 1 - 2/(e^{2x}+1); saturates correctly (+-inf -> +-1)
    float e = __expf(2.f * x);
    return 1.f - 2.f * __builtin_amdgcn_rcpf(e + 1.f);
}

// MFMA 16x16x32 f16 layouts (HW-verified):
//   A-frag: lane holds A[m = lane&15][k = (lane>>4)*8 + j], j=0..7
//   B-frag: lane holds B[k = (lane>>4)*8 + j][n = lane&15]
//   C/D   : lane holds D[row = (lane>>4)*4 + r][col = lane&15], r=0..3
// G = W · h^T: A = weight tile (rows = hidden units), B[k][n] = h[batch n][k].
__global__ __launch_bounds__(NT, 4)   // 4 waves/SIMD -> 2 blocks/CU
void rnn_mfma4(const float* __restrict__ x,
               const float* __restrict__ W_ih0, const float* __restrict__ W_hh0,
               const float* __restrict__ b_ih0, const float* __restrict__ b_hh0,
               const float* __restrict__ W_ih1, const float* __restrict__ W_hh1,
               const float* __restrict__ b_ih1, const float* __restrict__ b_hh1,
               const float* __restrict__ fc_w, const float* __restrict__ fc_b,
               float* __restrict__ out)
{
    __shared__ half_t h0s[2][BT * HP];
    __shared__ half_t h1s[2][BT * HP];
    __shared__ half_t xs[TSZ][BT * XP];   // ALL timesteps staged once: 28 KiB

    const int tid  = threadIdx.x;
    const int wave = tid >> 6;          // 0..7 -> row-tile [wave*16, wave*16+16)
    const int lane = tid & 63;
    const int ln   = lane & 15;
    const int quad = lane >> 4;
    const int kq   = quad * 8;
    const int b0   = blockIdx.x * BT;
    const int base = wave * 16;
    const int row  = base + ln;         // A-frag row (hidden unit)

    // ---- persistent weight A-fragments (loaded once): 13 frags ----
    v8h aWx, aW0[4], aW1i[4], aW1h[4];
    v4f bias0, bias1;
    {
        float4 p = *(const float4*)(b_ih0 + base + quad * 4);
        float4 q = *(const float4*)(b_hh0 + base + quad * 4);
        bias0 = (v4f){p.x + q.x, p.y + q.y, p.z + q.z, p.w + q.w};
        p = *(const float4*)(b_ih1 + base + quad * 4);
        q = *(const float4*)(b_hh1 + base + quad * 4);
        bias1 = (v4f){p.x + q.x, p.y + q.y, p.z + q.z, p.w + q.w};
    }
    {
        const float* pw = W_ih0 + row * ISZ + kq;      // kq<=24, kq+3<=27 in-row
        float4 a = *(const float4*)pw;
        float4 b = (kq < 24) ? *(const float4*)(pw + 4) : make_float4(0.f, 0.f, 0.f, 0.f);
        aWx = (v8h){(half_t)a.x, (half_t)a.y, (half_t)a.z, (half_t)a.w,
                    (half_t)b.x, (half_t)b.y, (half_t)b.z, (half_t)b.w};
    }
#pragma unroll
    for (int ks = 0; ks < 4; ++ks) {
        const float4* p0 = (const float4*)(W_hh0 + row * HSZ + ks * 32 + kq);
        const float4* p1 = (const float4*)(W_ih1 + row * HSZ + ks * 32 + kq);
        const float4* p2 = (const float4*)(W_hh1 + row * HSZ + ks * 32 + kq);
        float4 a = p0[0], b = p0[1];
        aW0[ks] = (v8h){(half_t)a.x, (half_t)a.y, (half_t)a.z, (half_t)a.w,
                        (half_t)b.x, (half_t)b.y, (half_t)b.z, (half_t)b.w};
        a = p1[0]; b = p1[1];
        aW1i[ks] = (v8h){(half_t)a.x, (half_t)a.y, (half_t)a.z, (half_t)a.w,
                         (half_t)b.x, (half_t)b.y, (half_t)b.z, (half_t)b.w};
        a = p2[0]; b = p2[1];
        aW1h[ks] = (v8h){(half_t)a.x, (half_t)a.y, (half_t)a.z, (half_t)a.w,
                         (half_t)b.x, (half_t)b.y, (half_t)b.z, (half_t)b.w};
    }

    // ---- stage ALL x for this block's 16 rows as f16, f32->f16, coalesced ----
    // 16 rows x 784 floats = 3136 float4; consecutive tid -> consecutive float4.
    // 784 = 196 float4/row; within a row, float4 F covers t = F/7, i = (F%7)*4
    // (28 % 4 == 0 so a float4 never straddles a timestep).
    {
        const float* xblk = x + (size_t)b0 * (TSZ * ISZ);
#pragma unroll
        for (int k = 0; k < 7; ++k) {
            const int F = tid + k * NT;
            if (F < BT * 196) {
                const int r   = F / 196;
                const int rem = F - r * 196;
                const int t   = rem / 7;
                const int i4  = (rem - t * 7) * 4;
                const float4 v = *(const float4*)(xblk + r * (TSZ * ISZ) + rem * 4);
                v4h p = {(half_t)v.x, (half_t)v.y, (half_t)v.z, (half_t)v.w};
                *(v4h*)&xs[t][r * XP + i4] = p;
            }
        }
        // zero the K-pad (cols 28..31) so 0*garbage can't make NaN in MFMA
        if (tid < TSZ * BT) {
            const int tt = tid >> 4, rr = tid & 15;
            *(v4h*)&xs[tt][rr * XP + ISZ] =
                (v4h){(half_t)0.f, (half_t)0.f, (half_t)0.f, (half_t)0.f};
        }
    }

    for (int idx = tid; idx < BT * HP; idx += NT)
        h1s[0][idx] = (half_t)0.f;              // h1(-1) = 0
    __syncthreads();

    // ---- h0(0) = tanh(W_ih0 x0^T + b0) -> h0s[0] ----
    {
        const v8h bx = *(const v8h*)&xs[0][ln * XP + kq];
        v4f a0 = bias0;
        a0 = __builtin_amdgcn_mfma_f32_16x16x32_f16(aWx, bx, a0, 0, 0, 0);
        v4h p = {(half_t)fast_tanh(a0[0]), (half_t)fast_tanh(a0[1]),
                 (half_t)fast_tanh(a0[2]), (half_t)fast_tanh(a0[3])};
        *(v4h*)&h0s[0][ln * HP + base + quad * 4] = p;
    }
    __syncthreads();

    // ---- main loop: segment t computes h1(t) and h0(t+1) ----
    // unroll 2 -> pr is compile-time in both bodies; all LDS addrs hoisted
#pragma unroll 2
    for (int t = 0; t < TSZ - 1; ++t) {
        const int pr = t & 1;

        // B-fragments from LDS (issue all reads up front)
        v8h bh0[4], bh1[4];
#pragma unroll
        for (int ks = 0; ks < 4; ++ks) {
            bh0[ks] = *(const v8h*)&h0s[pr][ln * HP + ks * 32 + kq];
            bh1[ks] = *(const v8h*)&h1s[pr][ln * HP + ks * 32 + kq];
        }
        const v8h bx = *(const v8h*)&xs[t + 1][ln * XP + kq];

        // three independent accumulator chains (5 / 4 / 4 deep)
        v4f a0  = bias0;
        v4f a1i = bias1;
        v4f a1h = (v4f){0.f, 0.f, 0.f, 0.f};
        a0 = __builtin_amdgcn_mfma_f32_16x16x32_f16(aWx, bx, a0, 0, 0, 0);
#pragma unroll
        for (int ks = 0; ks < 4; ++ks) {
            a1i = __builtin_amdgcn_mfma_f32_16x16x32_f16(aW1i[ks], bh0[ks], a1i, 0, 0, 0);
            a1h = __builtin_amdgcn_mfma_f32_16x16x32_f16(aW1h[ks], bh1[ks], a1h, 0, 0, 0);
            a0  = __builtin_amdgcn_mfma_f32_16x16x32_f16(aW0[ks],  bh0[ks], a0,  0, 0, 0);
        }
        const v4f a1 = a1i + a1h;

        // tanh + packed h writes
        {
            v4h p1 = {(half_t)fast_tanh(a1[0]), (half_t)fast_tanh(a1[1]),
                      (half_t)fast_tanh(a1[2]), (half_t)fast_tanh(a1[3])};
            *(v4h*)&h1s[pr ^ 1][ln * HP + base + quad * 4] = p1;
            v4h p0 = {(half_t)fast_tanh(a0[0]), (half_t)fast_tanh(a0[1]),
                      (half_t)fast_tanh(a0[2]), (half_t)fast_tanh(a0[3])};
            *(v4h*)&h0s[pr ^ 1][ln * HP + base + quad * 4] = p0;
        }

        __syncthreads();
    }

    // ---- final segment: h1(27) only -> h1s[0] ----
    {
        const int pr = (TSZ - 1) & 1;   // = 1
        v4f a1i = bias1;
        v4f a1h = (v4f){0.f, 0.f, 0.f, 0.f};
#pragma unroll
        for (int ks = 0; ks < 4; ++ks) {
            const v8h bh0 = *(const v8h*)&h0s[pr][ln * HP + ks * 32 + kq];
            const v8h bh1 = *(const v8h*)&h1s[pr][ln * HP + ks * 32 + kq];
            a1i = __builtin_amdgcn_mfma_f32_16x16x32_f16(aW1i[ks], bh0, a1i, 0, 0, 0);
            a1h = __builtin_amdgcn_mfma_f32_16x16x32_f16(aW1h[ks], bh1, a1h, 0, 0, 0);
        }
        const v4f a1 = a1i + a1h;
        v4h p1 = {(half_t)fast_tanh(a1[0]), (half_t)fast_tanh(a1[1]),
                  (half_t)fast_tanh(a1[2]), (half_t)fast_tanh(a1[3])};
        *(v4h*)&h1s[pr ^ 1][ln * HP + base + quad * 4] = p1;
    }
    __syncthreads();

    // ---- FC epilogue: out = h1(27) @ fc_w^T + fc_b ----
    if (tid < BT * CSZ) {
        const int m = tid / CSZ, cc = tid - m * CSZ;
        float s = fc_b[cc];
#pragma unroll
        for (int k8 = 0; k8 < HSZ / 8; ++k8) {
            const v8h hv = *(const v8h*)&h1s[0][m * HP + k8 * 8];
            const float4 w0 = *(const float4*)(fc_w + cc * HSZ + k8 * 8);
            const float4 w1 = *(const float4*)(fc_w + cc * HSZ + k8 * 8 + 4);
            s += (float)hv[0] * w0.x + (float)hv[1] * w0.y +
                 (float)hv[2] * w0.z + (float)hv[3] * w0.w +
                 (float)hv[4] * w1.x + (float)hv[5] * w1.y +
                 (float)hv[6] * w1.z + (float)hv[7] * w1.w;
        }
        out[(b0 + m) * CSZ + cc] = s;
    }
}

extern "C" void kernel_launch(void* const* d_in, const int* in_sizes, int n_in,
                              void* d_out, int out_size, void* d_ws, size_t ws_size,
                              hipStream_t stream) {
    const float* x     = (const float*)d_in[0];
    const float* W_ih0 = (const float*)d_in[1];
    const float* W_hh0 = (const float*)d_in[2];
    const float* b_ih0 = (const float*)d_in[3];
    const float* b_hh0 = (const float*)d_in[4];
    const float* W_ih1 = (const float*)d_in[5];
    const float* W_hh1 = (const float*)d_in[6];
    const float* b_ih1 = (const float*)d_in[7];
    const float* b_hh1 = (const float*)d_in[8];
    const float* fc_w  = (const float*)d_in[9];
    const float* fc_b  = (const float*)d_in[10];
    float* out = (float*)d_out;

    const int B = in_sizes[0] / (TSZ * ISZ);   // 8192
    dim3 grid(B / BT), block(NT);
    rnn_mfma4<<<grid, block, 0, stream>>>(x, W_ih0, W_hh0, b_ih0, b_hh0,
                                          W_ih1, W_hh1, b_ih1, b_hh1,
                                          fc_w, fc_b, out);
}